// Round 2
// baseline (128.216 us; speedup 1.0000x reference)
//
#include <hip/hip_runtime.h>
#include <hip/hip_bf16.h>
#include <stdint.h>

typedef short bf16x8 __attribute__((ext_vector_type(8)));
typedef float f32x4 __attribute__((ext_vector_type(4)));

#define DEVI static __device__ __forceinline__

constexpr int B_   = 32768;
constexpr int IN_  = 128;
constexpr int LF_  = 512;
constexpr int OUT_ = 32;
constexpr int NE_  = 48;   // 32 pi + 1 qb + 15 zero

// ---- workspace layout (bytes) ----
constexpr size_t OFF_XB  = 0;                   // 32768*128*2 = 8,388,608
constexpr size_t OFF_LT  = 8388608;             // 512*512*2   = 524,288
constexpr size_t OFF_W1  = OFF_LT + 524288;     // 512*128*2   = 131,072
constexpr size_t OFF_W2E = OFF_W1 + 131072;     // 48*512*2    = 49,152

DEVI void gl2lds16(const void* g, void* l) {
    __builtin_amdgcn_global_load_lds(
        (const __attribute__((address_space(1))) unsigned int*)g,
        (__attribute__((address_space(3))) unsigned int*)l,
        16, 0, 0);
}

// 4-chunk-per-row staged tile (BK=32): slot = row*4 + (c ^ (row&3))
DEVI bf16x8 frag4(const char* base, int row, int kofs) {
    int c = ((kofs >> 3) & 3) ^ (row & 3);
    return *(const bf16x8*)(base + (size_t)((row << 2) + c) * 16);
}
// phi LDS tile: 64 rows x 64 chunks; slot = row*64 + ((k>>3) ^ (row&7))
DEVI bf16x8 phiFrag(const char* p, int row, int kofs) {
    int c = (kofs >> 3) ^ (row & 7);
    return *(const bf16x8*)(p + (size_t)((row << 6) + c) * 16);
}
DEVI void phiStore(char* p, int row, int col, __hip_bfloat16 v) {
    int c = (col >> 3) ^ (row & 7);
    *(__hip_bfloat16*)(p + (size_t)((row << 6) + c) * 16 + (col & 7) * 2) = v;
}

// ---------------- prep: casts + Lt unpack + W2ext build ----------------
__global__ __launch_bounds__(256) void k_prep(
        const float* __restrict__ x,  const float* __restrict__ w1,
        const float* __restrict__ w2, const float* __restrict__ lv,
        const float* __restrict__ qb,
        __hip_bfloat16* __restrict__ xb, __hip_bfloat16* __restrict__ w1b,
        __hip_bfloat16* __restrict__ lt, __hip_bfloat16* __restrict__ w2e) {
    int gt = blockIdx.x * blockDim.x + threadIdx.x;
    int st = gridDim.x * blockDim.x;
    for (int i = gt; i < B_ * IN_; i += st) xb[i] = __float2bfloat16(x[i]);
    for (int i = gt; i < LF_ * IN_; i += st) w1b[i] = __float2bfloat16(w1[i]);
    for (int i = gt; i < NE_ * LF_; i += st) {
        int n = i >> 9, k = i & 511;
        float v = (n < OUT_) ? w2[n * LF_ + k] : (n == OUT_ ? qb[k] : 0.f);
        w2e[i] = __float2bfloat16(v);
    }
    for (int i = gt; i < LF_ * LF_; i += st) {
        int j = i >> 9, k = i & 511;  // Lt[j][k] = L[k][j], zero for k<j
        float v = (k >= j) ? lv[k * (k + 1) / 2 + j] : 0.f;
        lt[i] = __float2bfloat16(v);
    }
}

// ---------------- fused: phi in LDS -> pi, vf ----------------
// Per block: M=64 rows. LDS: phi 64KB | stageA 4KB | stageB 8KB | reduce 1.25KB
// -> 77.25 KB -> 2 blocks/CU, 8 waves/CU.
__global__ __launch_bounds__(256, 2) void k_fused(
        const __hip_bfloat16* __restrict__ xb, const __hip_bfloat16* __restrict__ w1b,
        const float* __restrict__ b1, const __hip_bfloat16* __restrict__ w2e,
        const __hip_bfloat16* __restrict__ lt, const float* __restrict__ qcp,
        float* __restrict__ pi, float* __restrict__ vf) {
    __shared__ char smem[79104];
    char*  phiB   = smem;
    char*  stageA = smem + 65536;
    char*  stageB = smem + 69632;
    float* vfb    = (float*)(smem + 77824);   // 64 f32: phi.qb
    float* vfp    = (float*)(smem + 78080);   // 4x64 f32: per-wave y partials

    const int tid = threadIdx.x, wv = tid >> 6, ln = tid & 63;
    const int cl = ln & 15, q = ln >> 4;
    const int m0 = blockIdx.x * 64;

    // ======== phase 1: phi(64x512) = tanh(x @ W1^T + b1) into LDS ========
    {
        const int wm = (wv & 1) * 32, wn = (wv >> 1) * 64;
        for (int n0 = 0; n0 < LF_; n0 += 128) {
            f32x4 acc[2][4] = {};
            for (int k0 = 0; k0 < IN_; k0 += 32) {
                __syncthreads();
                {   // x slab 64x32: 256 chunks
                    int slot = tid, row = slot >> 2, c = (slot & 3) ^ (row & 3);
                    gl2lds16(xb + (size_t)(m0 + row) * IN_ + k0 + c * 8,
                             stageA + (size_t)(wv * 64) * 16);
                }
#pragma unroll
                for (int it = 0; it < 2; ++it) {  // W1 slab 128x32: 512 chunks
                    int slot = it * 256 + tid, row = slot >> 2, c = (slot & 3) ^ (row & 3);
                    gl2lds16(w1b + (size_t)(n0 + row) * IN_ + k0 + c * 8,
                             stageB + (size_t)(it * 256 + wv * 64) * 16);
                }
                __syncthreads();
                bf16x8 af[2], bfr[4];
#pragma unroll
                for (int i = 0; i < 2; ++i) af[i]  = frag4(stageA, wm + i * 16 + cl, q * 8);
#pragma unroll
                for (int i = 0; i < 4; ++i) bfr[i] = frag4(stageB, wn + i * 16 + cl, q * 8);
#pragma unroll
                for (int mi = 0; mi < 2; ++mi)
#pragma unroll
                    for (int ni = 0; ni < 4; ++ni)
                        acc[mi][ni] = __builtin_amdgcn_mfma_f32_16x16x32_bf16(
                            af[mi], bfr[ni], acc[mi][ni], 0, 0, 0);
            }
            // epilogue: tanh -> phi LDS (C/D: col=lane&15, row=q*4+r)
#pragma unroll
            for (int ni = 0; ni < 4; ++ni) {
                int colg = n0 + wn + ni * 16 + cl;
                float bv = b1[colg];
#pragma unroll
                for (int mi = 0; mi < 2; ++mi)
#pragma unroll
                    for (int r = 0; r < 4; ++r) {
                        int row = wm + mi * 16 + q * 4 + r;
                        phiStore(phiB, row, colg,
                                 __float2bfloat16(tanhf(acc[mi][ni][r] + bv)));
                    }
            }
        }
    }
    __syncthreads();   // phi complete

    // ======== phase 2: pi = phi @ W2ext^T (B frags straight from L2) ========
    {
        const int wm = wv * 16;
        f32x4 a2[3] = {};
        for (int k0 = 0; k0 < LF_; k0 += 32) {
            bf16x8 a = phiFrag(phiB, wm + cl, k0 + q * 8);
#pragma unroll
            for (int ni = 0; ni < 3; ++ni) {
                bf16x8 b = *(const bf16x8*)(w2e + (size_t)(ni * 16 + cl) * LF_ + k0 + q * 8);
                a2[ni] = __builtin_amdgcn_mfma_f32_16x16x32_bf16(a, b, a2[ni], 0, 0, 0);
            }
        }
#pragma unroll
        for (int ni = 0; ni < 3; ++ni)
#pragma unroll
            for (int r = 0; r < 4; ++r) {
                int row = wm + q * 4 + r, col = ni * 16 + cl;
                float v = a2[ni][r];
                if (col < OUT_)       pi[(size_t)(m0 + row) * OUT_ + col] = v;
                else if (col == OUT_) vfb[row] = v;   // phi.qb
            }
    }

    // ======== phase 3: y = rowsum((phi @ L)^2), triangular K-skip ========
    {
        const int wn = wv * 32;
        float vacc[4][4] = {};   // [mi][r]
        for (int n0 = 0; n0 < LF_; n0 += 128) {
            f32x4 acc[4][2] = {};
            for (int k0 = n0; k0 < LF_; k0 += 32) {
                __syncthreads();
#pragma unroll
                for (int it = 0; it < 2; ++it) {  // Lt slab 128x32: 512 chunks
                    int slot = it * 256 + tid, row = slot >> 2, c = (slot & 3) ^ (row & 3);
                    gl2lds16(lt + (size_t)(n0 + row) * LF_ + k0 + c * 8,
                             stageB + (size_t)(it * 256 + wv * 64) * 16);
                }
                __syncthreads();
                bf16x8 bfr[2];
#pragma unroll
                for (int ni = 0; ni < 2; ++ni) bfr[ni] = frag4(stageB, wn + ni * 16 + cl, q * 8);
#pragma unroll
                for (int mi = 0; mi < 4; ++mi) {
                    bf16x8 a = phiFrag(phiB, mi * 16 + cl, k0 + q * 8);
#pragma unroll
                    for (int ni = 0; ni < 2; ++ni)
                        acc[mi][ni] = __builtin_amdgcn_mfma_f32_16x16x32_bf16(
                            a, bfr[ni], acc[mi][ni], 0, 0, 0);
                }
            }
#pragma unroll
            for (int mi = 0; mi < 4; ++mi)
#pragma unroll
                for (int r = 0; r < 4; ++r) {
                    float s = 0.f;
#pragma unroll
                    for (int ni = 0; ni < 2; ++ni) { float t = acc[mi][ni][r]; s += t * t; }
                    vacc[mi][r] += s;
                }
        }
        // reduce over the 16 col-lanes, then per-wave partial to LDS
#pragma unroll
        for (int mi = 0; mi < 4; ++mi)
#pragma unroll
            for (int r = 0; r < 4; ++r) {
                float v = vacc[mi][r];
                v += __shfl_xor(v, 1, 64);
                v += __shfl_xor(v, 2, 64);
                v += __shfl_xor(v, 4, 64);
                v += __shfl_xor(v, 8, 64);
                vacc[mi][r] = v;
            }
        if (cl == 0)
#pragma unroll
            for (int mi = 0; mi < 4; ++mi)
#pragma unroll
                for (int r = 0; r < 4; ++r)
                    vfp[wv * 64 + mi * 16 + q * 4 + r] = vacc[mi][r];
    }
    __syncthreads();
    if (tid < 64) {
        float v = vfb[tid] + qcp[0] +
                  vfp[tid] + vfp[64 + tid] + vfp[128 + tid] + vfp[192 + tid];
        vf[m0 + tid] = v;
    }
}

extern "C" void kernel_launch(void* const* d_in, const int* in_sizes, int n_in,
                              void* d_out, int out_size, void* d_ws, size_t ws_size,
                              hipStream_t stream) {
    const float* x  = (const float*)d_in[0];
    const float* w1 = (const float*)d_in[1];
    const float* b1 = (const float*)d_in[2];
    const float* w2 = (const float*)d_in[3];
    const float* lv = (const float*)d_in[4];
    const float* qb = (const float*)d_in[5];
    const float* qc = (const float*)d_in[6];

    char* ws = (char*)d_ws;
    __hip_bfloat16* xb  = (__hip_bfloat16*)(ws + OFF_XB);
    __hip_bfloat16* lt  = (__hip_bfloat16*)(ws + OFF_LT);
    __hip_bfloat16* w1b = (__hip_bfloat16*)(ws + OFF_W1);
    __hip_bfloat16* w2e = (__hip_bfloat16*)(ws + OFF_W2E);

    float* pi = (float*)d_out;
    float* vf = pi + (size_t)B_ * OUT_;

    k_prep <<<1024, 256, 0, stream>>>(x, w1, w2, lv, qb, xb, w1b, lt, w2e);
    k_fused<<<B_ / 64, 256, 0, stream>>>(xb, w1b, b1, w2e, lt, qc, pi, vf);
}

// Round 3
// 123.435 us; speedup vs baseline: 1.0387x; 1.0387x over previous
//
#include <hip/hip_runtime.h>
#include <hip/hip_bf16.h>
#include <stdint.h>

typedef short bf16x8 __attribute__((ext_vector_type(8)));
typedef float f32x4 __attribute__((ext_vector_type(4)));

#define DEVI static __device__ __forceinline__

constexpr int B_   = 32768;
constexpr int IN_  = 128;
constexpr int LF_  = 512;
constexpr int OUT_ = 32;
constexpr int NE_  = 48;   // 32 pi + 1 qb + 15 zero

// ---- workspace layout (bytes) ----
constexpr size_t OFF_LT  = 0;                   // 512*512*2 = 524,288
constexpr size_t OFF_W1  = 524288;              // 512*128*2 = 131,072
constexpr size_t OFF_W2E = OFF_W1 + 131072;     // 48*512*2  = 49,152

DEVI short f2bs(float f) { __hip_bfloat16 h = __float2bfloat16(f); return *(short*)&h; }

// fast tanh: 1 - 2/(e^{2v}+1); exact at both saturations, ~1e-6 abs err
DEVI float tanh_fast(float v) {
    float e = __expf(2.0f * v);
    return 1.0f - 2.0f * __builtin_amdgcn_rcpf(e + 1.0f);
}

// phi LDS tile: 64 rows x 64 chunks(16B); slot = row*64 + ((k>>3) ^ (row&7))
DEVI bf16x8 phiFrag(const char* p, int row, int kofs) {
    int c = (kofs >> 3) ^ (row & 7);
    return *(const bf16x8*)(p + (size_t)((row << 6) + c) * 16);
}
DEVI void phiStore(char* p, int row, int col, float v) {
    int c = (col >> 3) ^ (row & 7);
    *(short*)(p + (size_t)((row << 6) + c) * 16 + (col & 7) * 2) = f2bs(v);
}
// x LDS tile: 64 rows x 16 chunks; slot = row*16 + ((k>>3) ^ (row&15))
DEVI bf16x8 xFrag(const char* p, int row, int kofs) {
    int c = (kofs >> 3) ^ (row & 15);
    return *(const bf16x8*)(p + (size_t)((row << 4) + c) * 16);
}

// ---------------- prep: Lt transpose + W1 cast + W2ext build ----------------
// blocks 0-63: Lt 64x64 transpose tiles; 64-95: W1 cast; 96-127: W2ext.
__global__ __launch_bounds__(256) void k_prep(
        const float* __restrict__ w1, const float* __restrict__ w2,
        const float* __restrict__ lv, const float* __restrict__ qb,
        __hip_bfloat16* __restrict__ w1b, __hip_bfloat16* __restrict__ lt,
        __hip_bfloat16* __restrict__ w2e) {
    int b = blockIdx.x, tid = threadIdx.x;
    if (b < 64) {
        __shared__ float tbuf[64][65];
        int bj = b >> 3, bk = b & 7;
        for (int i = tid; i < 4096; i += 256) {
            int kk = i >> 6, jj = i & 63;
            int k = bk * 64 + kk, j = bj * 64 + jj;
            tbuf[kk][jj] = (k >= j) ? lv[k * (k + 1) / 2 + j] : 0.f;  // coalesced in jj
        }
        __syncthreads();
        for (int i = tid; i < 4096; i += 256) {
            int jj = i >> 6, kk = i & 63;
            lt[(size_t)(bj * 64 + jj) * LF_ + bk * 64 + kk] = __float2bfloat16(tbuf[kk][jj]);
        }
    } else if (b < 96) {
        int gt = (b - 64) * 256 + tid;                 // 8192 threads
        for (int i = gt; i < LF_ * IN_ / 4; i += 8192) {
            float4 v = ((const float4*)w1)[i];
            short4 s = { f2bs(v.x), f2bs(v.y), f2bs(v.z), f2bs(v.w) };
            ((short4*)w1b)[i] = s;
        }
    } else {
        int gt = (b - 96) * 256 + tid;
        for (int i = gt; i < NE_ * LF_; i += 8192) {
            int n = i >> 9, k = i & 511;
            float v = (n < OUT_) ? w2[n * LF_ + k] : (n == OUT_ ? qb[k] : 0.f);
            w2e[i] = __float2bfloat16(v);
        }
    }
}

// ---------------- fused: x->phi(LDS)->pi,vf ; zero inner barriers ----------------
// LDS: phi 64KB | stage 16KB (x tile, later aliased as vfb/vfp) = 80KB -> 2 blocks/CU
__global__ __launch_bounds__(256, 2) void k_fused(
        const float* __restrict__ x, const __hip_bfloat16* __restrict__ w1b,
        const float* __restrict__ b1, const __hip_bfloat16* __restrict__ w2e,
        const __hip_bfloat16* __restrict__ lt, const float* __restrict__ qcp,
        float* __restrict__ pi, float* __restrict__ vf) {
    __shared__ char smem[81920];
    char*  phiB  = smem;
    char*  stage = smem + 65536;
    float* vfb   = (float*)stage;          // 64 f32 (alias, valid after phase-1 barrier)
    float* vfp   = (float*)(stage + 256);  // 4x64 f32

    const int tid = threadIdx.x, wv = tid >> 6, ln = tid & 63;
    const int cl = ln & 15, q = ln >> 4;
    const int m0 = blockIdx.x * 64;

    // ---- phase 0: load+cast x tile (64x128 fp32 -> bf16) into LDS ----
#pragma unroll
    for (int it = 0; it < 4; ++it) {
        int slot = it * 256 + tid, row = slot >> 4, cg = slot & 15;
        const float4* p = (const float4*)(x + (size_t)(m0 + row) * IN_ + cg * 8);
        float4 u0 = p[0], u1 = p[1];
        bf16x8 pk;
        pk[0] = f2bs(u0.x); pk[1] = f2bs(u0.y); pk[2] = f2bs(u0.z); pk[3] = f2bs(u0.w);
        pk[4] = f2bs(u1.x); pk[5] = f2bs(u1.y); pk[6] = f2bs(u1.z); pk[7] = f2bs(u1.w);
        *(bf16x8*)(stage + (size_t)((row << 4) + (cg ^ (row & 15))) * 16) = pk;
    }
    __syncthreads();

    // ---- phase 1: phi = tanh(x @ W1^T + b1); wave owns 128-col strip ----
    {
        const int n0w = wv * 128;
#pragma unroll
        for (int ch = 0; ch < 2; ++ch) {
            f32x4 acc[4][4] = {};
#pragma unroll
            for (int k0 = 0; k0 < IN_; k0 += 32) {
                bf16x8 a[4], bfr[4];
#pragma unroll
                for (int mi = 0; mi < 4; ++mi) a[mi] = xFrag(stage, mi * 16 + cl, k0 + q * 8);
#pragma unroll
                for (int ni = 0; ni < 4; ++ni)
                    bfr[ni] = *(const bf16x8*)(
                        w1b + (size_t)(n0w + ch * 64 + ni * 16 + cl) * IN_ + k0 + q * 8);
#pragma unroll
                for (int mi = 0; mi < 4; ++mi)
#pragma unroll
                    for (int ni = 0; ni < 4; ++ni)
                        acc[mi][ni] = __builtin_amdgcn_mfma_f32_16x16x32_bf16(
                            a[mi], bfr[ni], acc[mi][ni], 0, 0, 0);
            }
#pragma unroll
            for (int ni = 0; ni < 4; ++ni) {
                int colg = n0w + ch * 64 + ni * 16 + cl;
                float bv = b1[colg];
#pragma unroll
                for (int mi = 0; mi < 4; ++mi)
#pragma unroll
                    for (int r = 0; r < 4; ++r)
                        phiStore(phiB, mi * 16 + q * 4 + r, colg,
                                 tanh_fast(acc[mi][ni][r] + bv));
            }
        }
    }
    __syncthreads();   // phi complete; x/stage dead -> vfb/vfp alias valid

    // ---- phase 2: pi = phi @ W2ext^T; wave owns 16 rows ----
    {
        const int wm = wv * 16;
        f32x4 a2[3] = {};
        for (int k0 = 0; k0 < LF_; k0 += 32) {
            bf16x8 a = phiFrag(phiB, wm + cl, k0 + q * 8);
#pragma unroll
            for (int ni = 0; ni < 3; ++ni) {
                bf16x8 b = *(const bf16x8*)(w2e + (size_t)(ni * 16 + cl) * LF_ + k0 + q * 8);
                a2[ni] = __builtin_amdgcn_mfma_f32_16x16x32_bf16(a, b, a2[ni], 0, 0, 0);
            }
        }
#pragma unroll
        for (int ni = 0; ni < 3; ++ni)
#pragma unroll
            for (int r = 0; r < 4; ++r) {
                int row = wm + q * 4 + r, col = ni * 16 + cl;
                float v = a2[ni][r];
                if (col < OUT_)       pi[(size_t)(m0 + row) * OUT_ + col] = v;
                else if (col == OUT_) vfb[row] = v;   // phi.qb
            }
    }

    // ---- phase 3: y = rowsum((phi @ L)^2); mirrored-pair tiles, no barriers ----
    {
        float vacc[4][4] = {};
#pragma unroll
        for (int s = 0; s < 2; ++s) {
            int tl[4] = { 16 * s + wv, 16 * s + 7 - wv, 16 * s + 8 + wv, 16 * s + 15 - wv };
            int ks[4];
#pragma unroll
            for (int j = 0; j < 4; ++j) ks[j] = (tl[j] * 16) & ~31;
            int kmin = min(min(ks[0], ks[1]), min(ks[2], ks[3]));
            f32x4 acc[4][4] = {};   // [tile][mi]
            for (int k0 = kmin; k0 < LF_; k0 += 32) {
                bf16x8 a[4];
#pragma unroll
                for (int mi = 0; mi < 4; ++mi) a[mi] = phiFrag(phiB, mi * 16 + cl, k0 + q * 8);
#pragma unroll
                for (int j = 0; j < 4; ++j) {
                    if (k0 >= ks[j]) {   // wave-uniform; rounding down exact (Lt zero-padded)
                        bf16x8 b = *(const bf16x8*)(
                            lt + (size_t)(tl[j] * 16 + cl) * LF_ + k0 + q * 8);
#pragma unroll
                        for (int mi = 0; mi < 4; ++mi)
                            acc[j][mi] = __builtin_amdgcn_mfma_f32_16x16x32_bf16(
                                a[mi], b, acc[j][mi], 0, 0, 0);
                    }
                }
            }
#pragma unroll
            for (int j = 0; j < 4; ++j)
#pragma unroll
                for (int mi = 0; mi < 4; ++mi)
#pragma unroll
                    for (int r = 0; r < 4; ++r) {
                        float t = acc[j][mi][r];
                        vacc[mi][r] += t * t;
                    }
        }
#pragma unroll
        for (int mi = 0; mi < 4; ++mi)
#pragma unroll
            for (int r = 0; r < 4; ++r) {
                float v = vacc[mi][r];
                v += __shfl_xor(v, 1, 64);
                v += __shfl_xor(v, 2, 64);
                v += __shfl_xor(v, 4, 64);
                v += __shfl_xor(v, 8, 64);
                vacc[mi][r] = v;
            }
        if (cl == 0)
#pragma unroll
            for (int mi = 0; mi < 4; ++mi)
#pragma unroll
                for (int r = 0; r < 4; ++r)
                    vfp[wv * 64 + mi * 16 + q * 4 + r] = vacc[mi][r];
    }
    __syncthreads();
    if (tid < 64)
        vf[m0 + tid] = vfb[tid] + qcp[0] +
                       vfp[tid] + vfp[64 + tid] + vfp[128 + tid] + vfp[192 + tid];
}

extern "C" void kernel_launch(void* const* d_in, const int* in_sizes, int n_in,
                              void* d_out, int out_size, void* d_ws, size_t ws_size,
                              hipStream_t stream) {
    const float* x  = (const float*)d_in[0];
    const float* w1 = (const float*)d_in[1];
    const float* b1 = (const float*)d_in[2];
    const float* w2 = (const float*)d_in[3];
    const float* lv = (const float*)d_in[4];
    const float* qb = (const float*)d_in[5];
    const float* qc = (const float*)d_in[6];

    char* ws = (char*)d_ws;
    __hip_bfloat16* lt  = (__hip_bfloat16*)(ws + OFF_LT);
    __hip_bfloat16* w1b = (__hip_bfloat16*)(ws + OFF_W1);
    __hip_bfloat16* w2e = (__hip_bfloat16*)(ws + OFF_W2E);

    float* pi = (float*)d_out;
    float* vf = pi + (size_t)B_ * OUT_;

    k_prep <<<128, 256, 0, stream>>>(w1, w2, lv, qb, w1b, lt, w2e);
    k_fused<<<B_ / 64, 256, 0, stream>>>(x, w1b, b1, w2e, lt, qc, pi, vf);
}

// Round 4
// 105.347 us; speedup vs baseline: 1.2171x; 1.1717x over previous
//
#include <hip/hip_runtime.h>
#include <hip/hip_bf16.h>
#include <stdint.h>

typedef short bf16x8 __attribute__((ext_vector_type(8)));
typedef float f32x4 __attribute__((ext_vector_type(4)));

#define DEVI static __device__ __forceinline__

constexpr int B_   = 32768;
constexpr int IN_  = 128;
constexpr int LF_  = 512;
constexpr int OUT_ = 32;

// ---- workspace layout (bytes) ----
// All B-side matrices stored in MFMA-fragment order:
//   chunk(tile,kstep) at base + chunk*64*16B; lane ln reads +ln*16B (coalesced).
// Fragment content for lane ln: row n = tile*16 + (ln&15), k = kstep*32 + (ln>>4)*8 .. +7.
constexpr size_t OFF_LTF = 0;                    // 32 tiles x 16 ks x 1KB = 524,288
constexpr size_t OFF_W1F = 524288;               // 32 tiles x 4 ks x 1KB  = 131,072
constexpr size_t OFF_W2F = OFF_W1F + 131072;     // 3 tiles x 16 ks x 1KB  = 49,152

DEVI short f2bs(float f) { __hip_bfloat16 h = __float2bfloat16(f); return *(short*)&h; }

// fast tanh: 1 - 2/(e^{2v}+1)
DEVI float tanh_fast(float v) {
    float e = __expf(2.0f * v);
    return 1.0f - 2.0f * __builtin_amdgcn_rcpf(e + 1.0f);
}

// coalesced fragment load: chunk = tile*ksteps + ks
DEVI bf16x8 fragGL(const __hip_bfloat16* base, int chunk, int ln) {
    return *(const bf16x8*)(base + ((size_t)chunk * 64 + ln) * 8);
}

// phi LDS tile: 64 rows x 64 chunks(16B); slot = row*64 + ((k>>3) ^ (row&7))
DEVI bf16x8 phiFrag(const char* p, int row, int kofs) {
    int c = (kofs >> 3) ^ (row & 7);
    return *(const bf16x8*)(p + (size_t)((row << 6) + c) * 16);
}
DEVI void phiStore(char* p, int row, int col, float v) {
    int c = (col >> 3) ^ (row & 7);
    *(short*)(p + (size_t)((row << 6) + c) * 16 + (col & 7) * 2) = f2bs(v);
}
// x LDS tile: 64 rows x 16 chunks; slot = row*16 + ((k>>3) ^ (row&15))
DEVI bf16x8 xFrag(const char* p, int row, int kofs) {
    int c = (kofs >> 3) ^ (row & 15);
    return *(const bf16x8*)(p + (size_t)((row << 4) + c) * 16);
}

// ---------------- prep: build fragment-order W1F / W2F / LTF ----------------
// one thread per 16B chunk: 8192 (w1f) + 3072 (w2f) + 32768 (ltf) = 44032
__global__ __launch_bounds__(256) void k_prep(
        const float* __restrict__ w1, const float* __restrict__ w2,
        const float* __restrict__ lv, const float* __restrict__ qb,
        __hip_bfloat16* __restrict__ w1f, __hip_bfloat16* __restrict__ w2f,
        __hip_bfloat16* __restrict__ ltf) {
    int cid = blockIdx.x * 256 + threadIdx.x;
    if (cid < 8192) {                       // W1F: nt(32) x ks(4) x ln(64)
        int ln = cid & 63, ks = (cid >> 6) & 3, nt = cid >> 8;
        int n = nt * 16 + (ln & 15), kb = ks * 32 + (ln >> 4) * 8;
        const float* src = w1 + (size_t)n * IN_ + kb;
        bf16x8 o;
#pragma unroll
        for (int i = 0; i < 8; ++i) o[i] = f2bs(src[i]);
        *(bf16x8*)(w1f + (size_t)cid * 8) = o;
    } else if (cid < 11264) {               // W2F: nt(3) x ks(16) x ln(64)
        int c2 = cid - 8192;
        int ln = c2 & 63, ks = (c2 >> 6) & 15, nt = c2 >> 10;
        int n = nt * 16 + (ln & 15), kb = ks * 32 + (ln >> 4) * 8;
        bf16x8 o;
#pragma unroll
        for (int i = 0; i < 8; ++i) {
            float v = (n < OUT_) ? w2[(size_t)n * LF_ + kb + i]
                                 : (n == OUT_ ? qb[kb + i] : 0.f);
            o[i] = f2bs(v);
        }
        *(bf16x8*)(w2f + (size_t)c2 * 8) = o;
    } else if (cid < 44032) {               // LTF: t(32) x ks(16) x ln(64)
        int c3 = cid - 11264;
        int ln = c3 & 63, ks = (c3 >> 6) & 15, t = c3 >> 10;
        int j = t * 16 + (ln & 15), kb = ks * 32 + (ln >> 4) * 8;
        bf16x8 o;
#pragma unroll
        for (int i = 0; i < 8; ++i) {
            int k = kb + i;                 // Lt[j][k] = L[k][j], zero for k<j
            o[i] = (k >= j) ? f2bs(lv[(size_t)k * (k + 1) / 2 + j]) : (short)0;
        }
        *(bf16x8*)(ltf + (size_t)c3 * 8) = o;
    }
}

// ---------------- fused: x->phi(LDS)->pi,vf ----------------
// 512 threads (8 waves), M=64. LDS: phi 64KB | stage 16KB (x, then vfb/vfp alias)
// = 80KB -> 2 blocks/CU = 16 waves/CU = 4 waves/SIMD.
__global__ __launch_bounds__(512, 4) void k_fused(
        const float* __restrict__ x, const __hip_bfloat16* __restrict__ w1f,
        const float* __restrict__ b1, const __hip_bfloat16* __restrict__ w2f,
        const __hip_bfloat16* __restrict__ ltf, const float* __restrict__ qcp,
        float* __restrict__ pi, float* __restrict__ vf) {
    __shared__ char smem[81920];
    char*  phiB  = smem;
    char*  stage = smem + 65536;
    float* vfb   = (float*)stage;          // 64 f32 (alias; valid after phase-1 barrier)
    float* vfp   = (float*)(stage + 256);  // 8x64 f32

    const int tid = threadIdx.x, wv = tid >> 6, ln = tid & 63;
    const int cl = ln & 15, q = ln >> 4;
    const int m0 = blockIdx.x * 64;

    // ---- phase 0: load+cast x tile (64x128 fp32 -> bf16) into LDS ----
#pragma unroll
    for (int it = 0; it < 2; ++it) {
        int slot = it * 512 + tid, row = slot >> 4, cg = slot & 15;
        const float4* p = (const float4*)(x + (size_t)(m0 + row) * IN_ + cg * 8);
        float4 u0 = p[0], u1 = p[1];
        bf16x8 pk;
        pk[0] = f2bs(u0.x); pk[1] = f2bs(u0.y); pk[2] = f2bs(u0.z); pk[3] = f2bs(u0.w);
        pk[4] = f2bs(u1.x); pk[5] = f2bs(u1.y); pk[6] = f2bs(u1.z); pk[7] = f2bs(u1.w);
        *(bf16x8*)(stage + (size_t)((row << 4) + (cg ^ (row & 15))) * 16) = pk;
    }
    __syncthreads();

    // ---- phase 1: phi = tanh(x @ W1^T + b1); wave owns 64-col strip ----
    {
        f32x4 acc[4][4] = {};
#pragma unroll
        for (int ks = 0; ks < 4; ++ks) {
            bf16x8 a[4], bfr[4];
#pragma unroll
            for (int mi = 0; mi < 4; ++mi) a[mi] = xFrag(stage, mi * 16 + cl, ks * 32 + q * 8);
#pragma unroll
            for (int ni = 0; ni < 4; ++ni)
                bfr[ni] = fragGL(w1f, (4 * wv + ni) * 4 + ks, ln);
#pragma unroll
            for (int mi = 0; mi < 4; ++mi)
#pragma unroll
                for (int ni = 0; ni < 4; ++ni)
                    acc[mi][ni] = __builtin_amdgcn_mfma_f32_16x16x32_bf16(
                        a[mi], bfr[ni], acc[mi][ni], 0, 0, 0);
        }
#pragma unroll
        for (int ni = 0; ni < 4; ++ni) {
            int colg = wv * 64 + ni * 16 + cl;
            float bv = b1[colg];
#pragma unroll
            for (int mi = 0; mi < 4; ++mi)
#pragma unroll
                for (int r = 0; r < 4; ++r)
                    phiStore(phiB, mi * 16 + q * 4 + r, colg,
                             tanh_fast(acc[mi][ni][r] + bv));
        }
    }
    __syncthreads();   // phi complete; x/stage dead -> vfb/vfp alias valid

    // ---- phase 2: pi = phi @ W2ext^T; 12 (m,n) wave-tiles over 8 waves ----
    {
        int ids[2] = { (wv < 4) ? 2 * wv : 8 + (wv - 4), (wv < 4) ? 2 * wv + 1 : -1 };
#pragma unroll
        for (int u = 0; u < 2; ++u) {
            int id = ids[u];
            if (id < 0) continue;
            int mi = id & 3, ni = id >> 2;
            f32x4 a2 = {};
            for (int ks = 0; ks < 16; ++ks) {
                bf16x8 a = phiFrag(phiB, mi * 16 + cl, ks * 32 + q * 8);
                bf16x8 b = fragGL(w2f, ni * 16 + ks, ln);
                a2 = __builtin_amdgcn_mfma_f32_16x16x32_bf16(a, b, a2, 0, 0, 0);
            }
#pragma unroll
            for (int r = 0; r < 4; ++r) {
                int row = mi * 16 + q * 4 + r, col = ni * 16 + cl;
                if (col < OUT_)       pi[(size_t)(m0 + row) * OUT_ + col] = a2[r];
                else if (col == OUT_) vfb[row] = a2[r];   // phi.qb
            }
        }
    }

    // ---- phase 3: y = rowsum((phi @ L)^2); mirrored tiles, coalesced B ----
    {
        int tl[4] = { wv, 15 - wv, 16 + wv, 31 - wv };
        int kstart[4];
#pragma unroll
        for (int j = 0; j < 4; ++j) kstart[j] = (tl[j] * 16) & ~31;  // exact: Lt zero-padded
        int kmin = min(min(kstart[0], kstart[1]), min(kstart[2], kstart[3]));
        f32x4 acc[4][4] = {};   // [tile][mi]
        for (int k0 = kmin; k0 < LF_; k0 += 32) {
            int ks = k0 >> 5;
            bf16x8 a[4];
#pragma unroll
            for (int mi = 0; mi < 4; ++mi) a[mi] = phiFrag(phiB, mi * 16 + cl, k0 + q * 8);
#pragma unroll
            for (int j = 0; j < 4; ++j) {
                if (k0 >= kstart[j]) {          // wave-uniform branch
                    bf16x8 b = fragGL(ltf, tl[j] * 16 + ks, ln);
#pragma unroll
                    for (int mi = 0; mi < 4; ++mi)
                        acc[j][mi] = __builtin_amdgcn_mfma_f32_16x16x32_bf16(
                            a[mi], b, acc[j][mi], 0, 0, 0);
                }
            }
        }
        float vacc[4][4];
#pragma unroll
        for (int mi = 0; mi < 4; ++mi)
#pragma unroll
            for (int r = 0; r < 4; ++r) {
                float s = 0.f;
#pragma unroll
                for (int j = 0; j < 4; ++j) { float t = acc[j][mi][r]; s += t * t; }
                s += __shfl_xor(s, 1, 64);
                s += __shfl_xor(s, 2, 64);
                s += __shfl_xor(s, 4, 64);
                s += __shfl_xor(s, 8, 64);
                vacc[mi][r] = s;
            }
        if (cl == 0)
#pragma unroll
            for (int mi = 0; mi < 4; ++mi)
#pragma unroll
                for (int r = 0; r < 4; ++r)
                    vfp[wv * 64 + mi * 16 + q * 4 + r] = vacc[mi][r];
    }
    __syncthreads();
    if (tid < 64) {
        float v = vfb[tid] + qcp[0];
#pragma unroll
        for (int w = 0; w < 8; ++w) v += vfp[w * 64 + tid];
        vf[m0 + tid] = v;
    }
}

extern "C" void kernel_launch(void* const* d_in, const int* in_sizes, int n_in,
                              void* d_out, int out_size, void* d_ws, size_t ws_size,
                              hipStream_t stream) {
    const float* x  = (const float*)d_in[0];
    const float* w1 = (const float*)d_in[1];
    const float* b1 = (const float*)d_in[2];
    const float* w2 = (const float*)d_in[3];
    const float* lv = (const float*)d_in[4];
    const float* qb = (const float*)d_in[5];
    const float* qc = (const float*)d_in[6];

    char* ws = (char*)d_ws;
    __hip_bfloat16* ltf = (__hip_bfloat16*)(ws + OFF_LTF);
    __hip_bfloat16* w1f = (__hip_bfloat16*)(ws + OFF_W1F);
    __hip_bfloat16* w2f = (__hip_bfloat16*)(ws + OFF_W2F);

    float* pi = (float*)d_out;
    float* vf = pi + (size_t)B_ * OUT_;

    k_prep <<<172, 256, 0, stream>>>(w1, w2, lv, qb, w1f, w2f, ltf);
    k_fused<<<B_ / 64, 512, 0, stream>>>(x, w1f, b1, w2f, ltf, qc, pi, vf);
}